// Round 2
// baseline (8626.593 us; speedup 1.0000x reference)
//
#include <hip/hip_runtime.h>
#include <hip/hip_bf16.h>

// Problem constants (AKT core): B=16, S=512, D=512, H=8, DFF=2048, NB=2, L=6
#define Bsz  16
#define Sl   512
#define Dm   512
#define Hn   8
#define DKh  64
#define DFFn 2048
#define MROWS (Bsz * Sl)      // 8192
#define NEGV (-1e32f)

// ---------------------------------------------------------------------------
// copy f32
// ---------------------------------------------------------------------------
__global__ void k_copy(const float* __restrict__ in, float* __restrict__ out, int n) {
    int i = blockIdx.x * 256 + threadIdx.x;
    if (i < n) out[i] = in[i];
}

// ---------------------------------------------------------------------------
// GEMM: C[M,N] = A[M,K] @ W[K,N] + bias[N], all f32, optional ReLU.
// 64x64 tile, BK=16, 256 threads, 4x4 micro-tile. Correctness-first baseline.
// ---------------------------------------------------------------------------
template <int RELU>
__global__ __launch_bounds__(256) void k_gemm(
    const float* __restrict__ A, const float* __restrict__ W,
    const float* __restrict__ bias, float* __restrict__ C,
    int M, int N, int K)
{
    __shared__ float As[16][64];
    __shared__ float Bs[16][64];

    int tid = threadIdx.x;
    int tx = tid & 15, ty = tid >> 4;          // 16x16 thread grid
    int n0 = blockIdx.x * 64, m0 = blockIdx.y * 64;

    int am = tid >> 2;            // 0..63  (row within A tile)
    int ak = (tid & 3) * 4;       // 0,4,8,12
    int bk = tid >> 4;            // 0..15  (row within W tile)
    int bn = (tid & 15) * 4;      // 0..60

    float acc[4][4] = {};

    for (int k0 = 0; k0 < K; k0 += 16) {
        float4 av = *(const float4*)(A + (size_t)(m0 + am) * K + k0 + ak);
        float4 wv = *(const float4*)(W + (size_t)(k0 + bk) * N + n0 + bn);
        __syncthreads();
        As[ak + 0][am] = av.x;
        As[ak + 1][am] = av.y;
        As[ak + 2][am] = av.z;
        As[ak + 3][am] = av.w;
        *(float4*)&Bs[bk][bn] = wv;
        __syncthreads();
#pragma unroll
        for (int k = 0; k < 16; ++k) {
            float4 a = *(const float4*)&As[k][ty * 4];
            float4 b = *(const float4*)&Bs[k][tx * 4];
            acc[0][0] += a.x * b.x; acc[0][1] += a.x * b.y; acc[0][2] += a.x * b.z; acc[0][3] += a.x * b.w;
            acc[1][0] += a.y * b.x; acc[1][1] += a.y * b.y; acc[1][2] += a.y * b.z; acc[1][3] += a.y * b.w;
            acc[2][0] += a.z * b.x; acc[2][1] += a.z * b.y; acc[2][2] += a.z * b.z; acc[2][3] += a.z * b.w;
            acc[3][0] += a.w * b.x; acc[3][1] += a.w * b.y; acc[3][2] += a.w * b.z; acc[3][3] += a.w * b.w;
        }
    }

    float4 b4 = *(const float4*)(bias + n0 + tx * 4);
#pragma unroll
    for (int i2 = 0; i2 < 4; ++i2) {
        float4 o;
        o.x = acc[i2][0] + b4.x;
        o.y = acc[i2][1] + b4.y;
        o.z = acc[i2][2] + b4.z;
        o.w = acc[i2][3] + b4.w;
        if (RELU) {
            o.x = fmaxf(o.x, 0.f); o.y = fmaxf(o.y, 0.f);
            o.z = fmaxf(o.z, 0.f); o.w = fmaxf(o.w, 0.f);
        }
        *(float4*)(C + (size_t)(m0 + ty * 4 + i2) * N + n0 + tx * 4) = o;
    }
}

// ---------------------------------------------------------------------------
// AKT attention with distance-decay. One wave per (b,h,i) row; 4 waves/block.
// Q doubles as K (kq_same=True and query==key_ in every layer call).
// Q,V layout: [B,S,D] f32 with head h at columns h*64..h*64+63.
// ---------------------------------------------------------------------------
__global__ __launch_bounds__(256) void k_attn(
    const float* __restrict__ Q, const float* __restrict__ V,
    float* __restrict__ O, const float* __restrict__ gam, int maskflag)
{
    __shared__ float pp[4][Sl];
    __shared__ float qs[4][DKh];
    int tid = threadIdx.x;
    int w = tid >> 6, lane = tid & 63;
    int row = blockIdx.x * 4 + w;        // (b*H + h)*S + i
    int b = row >> 12;
    int h = (row >> 9) & 7;
    int i = row & 511;

    size_t qoff = ((size_t)(b * Sl + i)) * Dm + h * DKh;
    qs[w][lane] = Q[qoff + lane];
    __syncthreads();

    int jmax = maskflag ? i : (i - 1);   // mask: j<=i (flag=1) or j<i (flag=0)

    // scores (registers, lane owns contiguous j = lane*8 .. lane*8+7)
    float sc[8];
#pragma unroll
    for (int r = 0; r < 8; ++r) {
        int j = lane * 8 + r;
        float s = NEGV;
        if (j <= jmax) {
            const float* kr = Q + ((size_t)(b * Sl + j)) * Dm + h * DKh;
            float acc = 0.f;
#pragma unroll
            for (int d4 = 0; d4 < 16; ++d4) {
                float4 kv = *(const float4*)(kr + d4 * 4);
                acc += qs[w][d4 * 4 + 0] * kv.x + qs[w][d4 * 4 + 1] * kv.y
                     + qs[w][d4 * 4 + 2] * kv.z + qs[w][d4 * 4 + 3] * kv.w;
            }
            s = acc * 0.125f;   // 1/sqrt(64)
        }
        sc[r] = s;
    }

    // softmax #1 -> p (then masked)
    float m = sc[0];
#pragma unroll
    for (int r = 1; r < 8; ++r) m = fmaxf(m, sc[r]);
#pragma unroll
    for (int off = 32; off >= 1; off >>= 1) m = fmaxf(m, __shfl_xor(m, off));
    float p[8], Z = 0.f;
#pragma unroll
    for (int r = 0; r < 8; ++r) { p[r] = __expf(sc[r] - m); Z += p[r]; }
#pragma unroll
    for (int off = 32; off >= 1; off >>= 1) Z += __shfl_xor(Z, off);
    float inv = 1.f / Z;

    // masked p, local inclusive cumsum
    float cs[8], run = 0.f;
#pragma unroll
    for (int r = 0; r < 8; ++r) {
        int j = lane * 8 + r;
        float pr = (j <= jmax) ? p[r] * inv : 0.f;
        run += pr;
        cs[r] = run;
    }
    // wave inclusive scan of per-lane totals
    float sl2 = run;
#pragma unroll
    for (int off = 1; off < 64; off <<= 1) {
        float nv = __shfl_up(sl2, off);
        if (lane >= off) sl2 += nv;
    }
    float excl = sl2 - run;
    float tot = __shfl(sl2, 63);

    // gamma -> g = -softplus(gamma_h)
    float gm = gam[h];
    float sp = (gm > 15.f) ? gm : log1pf(__expf(gm));
    float g = -sp;

    // distance-decayed scores
#pragma unroll
    for (int r = 0; r < 8; ++r) {
        int j = lane * 8 + r;
        float dc = excl + cs[r];
        float pos = fabsf((float)(i - j));
        float dd = fmaxf((tot - dc) * pos, 0.f);
        float te = __expf(sqrtf(dd) * g);
        te = fminf(fmaxf(te, 1e-5f), 1e5f);
        sc[r] = (j <= jmax) ? sc[r] * te : NEGV;
    }

    // softmax #2 -> attn
    m = sc[0];
#pragma unroll
    for (int r = 1; r < 8; ++r) m = fmaxf(m, sc[r]);
#pragma unroll
    for (int off = 32; off >= 1; off >>= 1) m = fmaxf(m, __shfl_xor(m, off));
    Z = 0.f;
#pragma unroll
    for (int r = 0; r < 8; ++r) { p[r] = __expf(sc[r] - m); Z += p[r]; }
#pragma unroll
    for (int off = 32; off >= 1; off >>= 1) Z += __shfl_xor(Z, off);
    inv = 1.f / Z;

    int zp = (maskflag == 0) && (i == 0);   // zero_pad on row 0
#pragma unroll
    for (int r = 0; r < 8; ++r) {
        float a = p[r] * inv;
        if (zp) a = 0.f;
        pp[w][lane * 8 + r] = a;
    }
    __syncthreads();

    // O_row = attn @ V   (lane = head dim d)
    float accd = 0.f;
    const float* vbp = V + (size_t)b * Sl * Dm + h * DKh + lane;
    for (int j = 0; j <= jmax; ++j)
        accd += pp[w][j] * vbp[(size_t)j * Dm];
    O[qoff + lane] = accd;
}

// ---------------------------------------------------------------------------
// Residual + LayerNorm: Out = LN(Xn + Rr) * g + b   (rows of 512, wave/row)
// ---------------------------------------------------------------------------
__global__ __launch_bounds__(256) void k_ln(
    const float* __restrict__ Xn, const float* __restrict__ Rr,
    const float* __restrict__ gw, const float* __restrict__ bw,
    float* __restrict__ Out)
{
    int tid = threadIdx.x;
    int w = tid >> 6, lane = tid & 63;
    int row = blockIdx.x * 4 + w;
    const float* xr = Xn + (size_t)row * Dm;
    const float* rr = Rr + (size_t)row * Dm;
    float v[8], sum = 0.f;
#pragma unroll
    for (int r = 0; r < 8; ++r) {
        int c = lane + r * 64;
        v[r] = xr[c] + rr[c];
        sum += v[r];
    }
#pragma unroll
    for (int off = 32; off >= 1; off >>= 1) sum += __shfl_xor(sum, off);
    float mu = sum * (1.f / 512.f);
    float var = 0.f;
#pragma unroll
    for (int r = 0; r < 8; ++r) { float d = v[r] - mu; var += d * d; }
#pragma unroll
    for (int off = 32; off >= 1; off >>= 1) var += __shfl_xor(var, off);
    float rs = rsqrtf(var * (1.f / 512.f) + 1e-5f);
    float* orow = Out + (size_t)row * Dm;
#pragma unroll
    for (int r = 0; r < 8; ++r) {
        int c = lane + r * 64;
        orow[c] = (v[r] - mu) * rs * gw[c] + bw[c];
    }
}

// ---------------------------------------------------------------------------
extern "C" void kernel_launch(void* const* d_in, const int* in_sizes, int n_in,
                              void* d_out, int out_size, void* d_ws, size_t ws_size,
                              hipStream_t stream)
{
    const float* q_emb  = (const float*)d_in[0];
    const float* qa_emb = (const float*)d_in[1];
    const float* Wk  = (const float*)d_in[3];
    const float* bk  = (const float*)d_in[4];
    const float* Wv  = (const float*)d_in[5];
    const float* bv  = (const float*)d_in[6];
    const float* Wo  = (const float*)d_in[7];
    const float* bo  = (const float*)d_in[8];
    const float* gam = (const float*)d_in[9];
    const float* l1g = (const float*)d_in[10];
    const float* l1b = (const float*)d_in[11];
    const float* W1  = (const float*)d_in[12];
    const float* b1  = (const float*)d_in[13];
    const float* W2  = (const float*)d_in[14];
    const float* b2  = (const float*)d_in[15];
    const float* l2g = (const float*)d_in[16];
    const float* l2b = (const float*)d_in[17];
    float* outp = (float*)d_out;

    const size_t NE = (size_t)MROWS * Dm;   // 4194304 elems per activation buf
    float* ws   = (float*)d_ws;
    float* xbuf = ws;                       // persistent x
    float* ybuf = xbuf + NE;                // persistent y
    float* t2   = ybuf + NE;                // proj / FFN output temp
    float* region = t2 + NE;                // 4*NE scratch region
    float* qb = region;                     // q (=k) heads
    float* vb = region + NE;                // v heads
    float* t1 = region + 2 * NE;            // attention output heads
    float* fb = region;                     // FFN hidden [8192, 2048] (4*NE)
    // total: 7*NE floats = 117.4 MB

    const int n = (int)NE;
    k_copy<<<n / 256, 256, 0, stream>>>(q_emb,  xbuf, n);
    k_copy<<<n / 256, 256, 0, stream>>>(qa_emb, ybuf, n);

    auto gemm = [&](const float* A, const float* W, const float* bias, float* C,
                    int M, int N, int K, bool relu) {
        dim3 grid(N / 64, M / 64);
        if (relu) k_gemm<1><<<grid, 256, 0, stream>>>(A, W, bias, C, M, N, K);
        else      k_gemm<0><<<grid, 256, 0, stream>>>(A, W, bias, C, M, N, K);
    };

    auto layer = [&](int l, int maskflag, float* Xq, float* Xv, bool apply_pos) {
        size_t wO = (size_t)l * Dm * Dm;
        // q-projection (also serves as k: query==key_ and kq_same=True)
        gemm(Xq, Wk + wO, bk + l * Dm, qb, MROWS, Dm, Dm, false);
        gemm(Xv, Wv + wO, bv + l * Dm, vb, MROWS, Dm, Dm, false);
        k_attn<<<(Bsz * Hn * Sl) / 4, 256, 0, stream>>>(qb, vb, t1, gam + l * Hn, maskflag);
        gemm(t1, Wo + wO, bo + l * Dm, t2, MROWS, Dm, Dm, false);
        k_ln<<<MROWS / 4, 256, 0, stream>>>(t2, Xq, l1g + l * Dm, l1b + l * Dm, Xq);
        if (apply_pos) {
            gemm(Xq, W1 + (size_t)l * Dm * DFFn, b1 + l * DFFn, fb, MROWS, DFFn, Dm, true);
            gemm(fb, W2 + (size_t)l * DFFn * Dm, b2 + l * Dm, t2, MROWS, Dm, DFFn, false);
            k_ln<<<MROWS / 4, 256, 0, stream>>>(t2, Xq, l2g + l * Dm, l2b + l * Dm, Xq);
        }
    };

    // blocks_1: self-attn on y, mask=1, FFN
    layer(0, 1, ybuf, ybuf, true);
    layer(1, 1, ybuf, ybuf, true);
    // blocks_2: (mask=1, no FFN) then (mask=0, values=y, FFN), twice
    layer(2, 1, xbuf, xbuf, false);
    layer(3, 0, xbuf, ybuf, true);
    layer(4, 1, xbuf, xbuf, false);
    layer(5, 0, xbuf, ybuf, true);

    // outputs: (x, y) concatenated
    k_copy<<<n / 256, 256, 0, stream>>>(xbuf, outp, n);
    k_copy<<<n / 256, 256, 0, stream>>>(ybuf, outp + NE, n);
}

// Round 3
// 5611.536 us; speedup vs baseline: 1.5373x; 1.5373x over previous
//
#include <hip/hip_runtime.h>
#include <hip/hip_bf16.h>

// Problem constants (AKT core): B=16, S=512, D=512, H=8, DFF=2048, NB=2, L=6
#define Bsz  16
#define Sl   512
#define Dm   512
#define Hn   8
#define DKh  64
#define DFFn 2048
#define MROWS (Bsz * Sl)      // 8192
#define NEGV (-1e32f)

// ---------------------------------------------------------------------------
// copy f32
// ---------------------------------------------------------------------------
__global__ void k_copy(const float* __restrict__ in, float* __restrict__ out, int n) {
    int i = blockIdx.x * 256 + threadIdx.x;
    if (i < n) out[i] = in[i];
}

// ---------------------------------------------------------------------------
// GEMM: C[M,N] = A[M,K] @ W[K,N] + bias[N], all f32, optional ReLU.
// 64x64 tile, BK=16, 256 threads, 4x4 micro-tile. (MFMA upgrade next round.)
// ---------------------------------------------------------------------------
template <int RELU>
__global__ __launch_bounds__(256) void k_gemm(
    const float* __restrict__ A, const float* __restrict__ W,
    const float* __restrict__ bias, float* __restrict__ C,
    int M, int N, int K)
{
    __shared__ float As[16][64];
    __shared__ float Bs[16][64];

    int tid = threadIdx.x;
    int tx = tid & 15, ty = tid >> 4;          // 16x16 thread grid
    int n0 = blockIdx.x * 64, m0 = blockIdx.y * 64;

    int am = tid >> 2;            // 0..63  (row within A tile)
    int ak = (tid & 3) * 4;       // 0,4,8,12
    int bk = tid >> 4;            // 0..15  (row within W tile)
    int bn = (tid & 15) * 4;      // 0..60

    float acc[4][4] = {};

    for (int k0 = 0; k0 < K; k0 += 16) {
        float4 av = *(const float4*)(A + (size_t)(m0 + am) * K + k0 + ak);
        float4 wv = *(const float4*)(W + (size_t)(k0 + bk) * N + n0 + bn);
        __syncthreads();
        As[ak + 0][am] = av.x;
        As[ak + 1][am] = av.y;
        As[ak + 2][am] = av.z;
        As[ak + 3][am] = av.w;
        *(float4*)&Bs[bk][bn] = wv;
        __syncthreads();
#pragma unroll
        for (int k = 0; k < 16; ++k) {
            float4 a = *(const float4*)&As[k][ty * 4];
            float4 b = *(const float4*)&Bs[k][tx * 4];
            acc[0][0] += a.x * b.x; acc[0][1] += a.x * b.y; acc[0][2] += a.x * b.z; acc[0][3] += a.x * b.w;
            acc[1][0] += a.y * b.x; acc[1][1] += a.y * b.y; acc[1][2] += a.y * b.z; acc[1][3] += a.y * b.w;
            acc[2][0] += a.z * b.x; acc[2][1] += a.z * b.y; acc[2][2] += a.z * b.z; acc[2][3] += a.z * b.w;
            acc[3][0] += a.w * b.x; acc[3][1] += a.w * b.y; acc[3][2] += a.w * b.z; acc[3][3] += a.w * b.w;
        }
    }

    float4 b4 = *(const float4*)(bias + n0 + tx * 4);
#pragma unroll
    for (int i2 = 0; i2 < 4; ++i2) {
        float4 o;
        o.x = acc[i2][0] + b4.x;
        o.y = acc[i2][1] + b4.y;
        o.z = acc[i2][2] + b4.z;
        o.w = acc[i2][3] + b4.w;
        if (RELU) {
            o.x = fmaxf(o.x, 0.f); o.y = fmaxf(o.y, 0.f);
            o.z = fmaxf(o.z, 0.f); o.w = fmaxf(o.w, 0.f);
        }
        *(float4*)(C + (size_t)(m0 + ty * 4 + i2) * N + n0 + tx * 4) = o;
    }
}

// ---------------------------------------------------------------------------
// AKT attention, LDS-tiled. One block per (b, h, 16-row i-tile).
//   Phase 1: scores S = Q K^T / 8 into LDS (register-tiled, K staged via LDS)
//   Phase 2: per-row softmax -> cumsum -> distance decay -> softmax (wave-
//            private rows, shuffle-based; attn overwrites scores in LDS)
//   Phase 3: O = attn @ V, V-tiles streamed through LDS
// K == Q buffer (kq_same=True and query==key_ in every layer call).
// Causal trim: j-tiles beyond i0+16 are fully masked -> skipped.
// ---------------------------------------------------------------------------
__global__ __launch_bounds__(256) void k_attn(
    const float* __restrict__ Q, const float* __restrict__ V,
    float* __restrict__ O, const float* __restrict__ gam, int maskflag)
{
    __shared__ float Sc[16][516];      // scores/attn, rows wave-private
    __shared__ float Qt[64][20];       // Q tile transposed [d][row]
    __shared__ float KV[64 * 68];      // K tile transposed [d*68+j] / V tile [j*68+d]

    int tid = threadIdx.x;
    int w = tid >> 6, lane = tid & 63;
    int tile = blockIdx.x & 31;
    int bh   = blockIdx.x >> 5;
    int b = bh >> 3, h = bh & 7;
    int i0 = tile * 16;
    int jtc = (i0 + 16 + 63) >> 6;     // # of 64-wide j-tiles with any valid j

    const float* Qbase = Q + (size_t)b * Sl * Dm + h * DKh;
    const float* Vbase = V + (size_t)b * Sl * Dm + h * DKh;

    float gm = gam[h];
    float g = -((gm > 20.f) ? gm : log1pf(__expf(gm)));   // -softplus(gamma)

    // ---- stage Q tile transposed --------------------------------------
    {
        int row = tid >> 4;                 // 0..15
        int dq  = (tid & 15) * 4;           // 0..60
        float4 qv = *(const float4*)(Qbase + (size_t)(i0 + row) * Dm + dq);
        Qt[dq + 0][row] = qv.x; Qt[dq + 1][row] = qv.y;
        Qt[dq + 2][row] = qv.z; Qt[dq + 3][row] = qv.w;
    }
    __syncthreads();

    int rg = lane >> 4;        // k-dim split group (d = rg*16 + dd)
    int jj = lane & 15;        // j group (4 cols each)
    int r0 = w * 4;            // this wave's row base (4 rows)

    // ---- Phase 1: scores ----------------------------------------------
    for (int jt = 0; jt < jtc; ++jt) {
        int j0 = jt * 64;
        {   // stage K tile transposed: KV[d*68 + j]
            int jr = tid >> 2;              // 0..63
            int dq = (tid & 3) * 16;        // 0,16,32,48
            const float* src = Qbase + (size_t)(j0 + jr) * Dm + dq;
            float4 k0 = *(const float4*)(src + 0);
            float4 k1 = *(const float4*)(src + 4);
            float4 k2 = *(const float4*)(src + 8);
            float4 k3 = *(const float4*)(src + 12);
            float* kt = KV + jr;
            kt[(dq + 0) * 68] = k0.x; kt[(dq + 1) * 68] = k0.y;
            kt[(dq + 2) * 68] = k0.z; kt[(dq + 3) * 68] = k0.w;
            kt[(dq + 4) * 68] = k1.x; kt[(dq + 5) * 68] = k1.y;
            kt[(dq + 6) * 68] = k1.z; kt[(dq + 7) * 68] = k1.w;
            kt[(dq + 8) * 68] = k2.x; kt[(dq + 9) * 68] = k2.y;
            kt[(dq +10) * 68] = k2.z; kt[(dq +11) * 68] = k2.w;
            kt[(dq +12) * 68] = k3.x; kt[(dq +13) * 68] = k3.y;
            kt[(dq +14) * 68] = k3.z; kt[(dq +15) * 68] = k3.w;
        }
        __syncthreads();

        float acc[4][4] = {};
#pragma unroll
        for (int dd = 0; dd < 16; ++dd) {
            int d = rg * 16 + dd;
            float4 qv = *(const float4*)&Qt[d][r0];
            float4 kv = *(const float4*)&KV[d * 68 + jj * 4];
            acc[0][0] += qv.x * kv.x; acc[0][1] += qv.x * kv.y; acc[0][2] += qv.x * kv.z; acc[0][3] += qv.x * kv.w;
            acc[1][0] += qv.y * kv.x; acc[1][1] += qv.y * kv.y; acc[1][2] += qv.y * kv.z; acc[1][3] += qv.y * kv.w;
            acc[2][0] += qv.z * kv.x; acc[2][1] += qv.z * kv.y; acc[2][2] += qv.z * kv.z; acc[2][3] += qv.z * kv.w;
            acc[3][0] += qv.w * kv.x; acc[3][1] += qv.w * kv.y; acc[3][2] += qv.w * kv.z; acc[3][3] += qv.w * kv.w;
        }
        // reduce the 4-way k-split across rg groups
#pragma unroll
        for (int ri = 0; ri < 4; ++ri)
#pragma unroll
            for (int cj = 0; cj < 4; ++cj) {
                float v = acc[ri][cj];
                v += __shfl_xor(v, 16);
                v += __shfl_xor(v, 32);
                acc[ri][cj] = v;
            }
        if (rg == 0) {
#pragma unroll
            for (int ri = 0; ri < 4; ++ri) {
                float4 o = make_float4(acc[ri][0], acc[ri][1], acc[ri][2], acc[ri][3]);
                *(float4*)&Sc[r0 + ri][j0 + jj * 4] = o;
            }
        }
        __syncthreads();
    }

    // ---- Phase 2: softmax -> cumsum -> decay -> softmax (wave-private) --
    for (int q = 0; q < 4; ++q) {
        int r = r0 + q;
        int i = i0 + r;
        int jmax = maskflag ? i : (i - 1);

        float4 s0 = *(float4*)&Sc[r][lane * 8];
        float4 s1 = *(float4*)&Sc[r][lane * 8 + 4];
        float s[8] = {s0.x, s0.y, s0.z, s0.w, s1.x, s1.y, s1.z, s1.w};
#pragma unroll
        for (int k = 0; k < 8; ++k) {
            int j = lane * 8 + k;
            s[k] = (j <= jmax) ? s[k] * 0.125f : NEGV;
        }
        float m = s[0];
#pragma unroll
        for (int k = 1; k < 8; ++k) m = fmaxf(m, s[k]);
#pragma unroll
        for (int off = 32; off >= 1; off >>= 1) m = fmaxf(m, __shfl_xor(m, off));
        float p[8], Z = 0.f;
#pragma unroll
        for (int k = 0; k < 8; ++k) { p[k] = __expf(s[k] - m); Z += p[k]; }
#pragma unroll
        for (int off = 32; off >= 1; off >>= 1) Z += __shfl_xor(Z, off);
        float inv = 1.f / Z;

        float cs[8], run = 0.f;
#pragma unroll
        for (int k = 0; k < 8; ++k) {
            int j = lane * 8 + k;
            float pm = (j <= jmax) ? p[k] * inv : 0.f;
            run += pm;
            cs[k] = run;
        }
        float sl = run;
#pragma unroll
        for (int off = 1; off < 64; off <<= 1) {
            float nv = __shfl_up(sl, off);
            if (lane >= off) sl += nv;
        }
        float excl = sl - run;
        float tot = __shfl(sl, 63);

#pragma unroll
        for (int k = 0; k < 8; ++k) {
            int j = lane * 8 + k;
            float dc = excl + cs[k];
            float pos = fabsf((float)(i - j));
            float dd = fmaxf((tot - dc) * pos, 0.f);
            float te = __expf(sqrtf(dd) * g);
            te = fminf(fmaxf(te, 1e-5f), 1e5f);
            s[k] = (j <= jmax) ? s[k] * te : NEGV;
        }

        m = s[0];
#pragma unroll
        for (int k = 1; k < 8; ++k) m = fmaxf(m, s[k]);
#pragma unroll
        for (int off = 32; off >= 1; off >>= 1) m = fmaxf(m, __shfl_xor(m, off));
        Z = 0.f;
#pragma unroll
        for (int k = 0; k < 8; ++k) { p[k] = __expf(s[k] - m); Z += p[k]; }
#pragma unroll
        for (int off = 32; off >= 1; off >>= 1) Z += __shfl_xor(Z, off);
        inv = 1.f / Z;

        int zp = (maskflag == 0) && (i == 0);
        float4 a0, a1;
        a0.x = zp ? 0.f : p[0] * inv; a0.y = zp ? 0.f : p[1] * inv;
        a0.z = zp ? 0.f : p[2] * inv; a0.w = zp ? 0.f : p[3] * inv;
        a1.x = zp ? 0.f : p[4] * inv; a1.y = zp ? 0.f : p[5] * inv;
        a1.z = zp ? 0.f : p[6] * inv; a1.w = zp ? 0.f : p[7] * inv;
        *(float4*)&Sc[r][lane * 8]     = a0;
        *(float4*)&Sc[r][lane * 8 + 4] = a1;
    }

    // ---- Phase 3: O = attn @ V ----------------------------------------
    int rr = lane >> 4;            // 0..3 (row within wave)
    int dg = lane & 15;            // d group (4 floats)
    float4 oacc = make_float4(0.f, 0.f, 0.f, 0.f);
    int r = r0 + rr;

    for (int jt = 0; jt < jtc; ++jt) {
        int j0 = jt * 64;
        __syncthreads();           // all waves done with previous KV use
        {   // stage V tile row-major: KV[j*68 + d]
            int jr = tid >> 2;
            int dq = (tid & 3) * 16;
            const float* src = Vbase + (size_t)(j0 + jr) * Dm + dq;
            float4 v0 = *(const float4*)(src + 0);
            float4 v1 = *(const float4*)(src + 4);
            float4 v2 = *(const float4*)(src + 8);
            float4 v3 = *(const float4*)(src + 12);
            float* vs = KV + jr * 68 + dq;
            *(float4*)(vs + 0)  = v0;
            *(float4*)(vs + 4)  = v1;
            *(float4*)(vs + 8)  = v2;
            *(float4*)(vs + 12) = v3;
        }
        __syncthreads();
#pragma unroll 4
        for (int j = 0; j < 64; ++j) {
            float pbr = Sc[r][j0 + j];
            float4 v = *(float4*)&KV[j * 68 + dg * 4];
            oacc.x += pbr * v.x; oacc.y += pbr * v.y;
            oacc.z += pbr * v.z; oacc.w += pbr * v.w;
        }
    }

    float* dst = O + ((size_t)b * Sl + i0 + r) * Dm + h * DKh + dg * 4;
    *(float4*)dst = oacc;
}

// ---------------------------------------------------------------------------
// Residual + LayerNorm: Out = LN(Xn + Rr) * g + b   (rows of 512, wave/row)
// ---------------------------------------------------------------------------
__global__ __launch_bounds__(256) void k_ln(
    const float* __restrict__ Xn, const float* __restrict__ Rr,
    const float* __restrict__ gw, const float* __restrict__ bw,
    float* __restrict__ Out)
{
    int tid = threadIdx.x;
    int w = tid >> 6, lane = tid & 63;
    int row = blockIdx.x * 4 + w;
    const float* xr = Xn + (size_t)row * Dm;
    const float* rr = Rr + (size_t)row * Dm;
    float v[8], sum = 0.f;
#pragma unroll
    for (int r = 0; r < 8; ++r) {
        int c = lane + r * 64;
        v[r] = xr[c] + rr[c];
        sum += v[r];
    }
#pragma unroll
    for (int off = 32; off >= 1; off >>= 1) sum += __shfl_xor(sum, off);
    float mu = sum * (1.f / 512.f);
    float var = 0.f;
#pragma unroll
    for (int r = 0; r < 8; ++r) { float d = v[r] - mu; var += d * d; }
#pragma unroll
    for (int off = 32; off >= 1; off >>= 1) var += __shfl_xor(var, off);
    float rs = rsqrtf(var * (1.f / 512.f) + 1e-5f);
    float* orow = Out + (size_t)row * Dm;
#pragma unroll
    for (int r = 0; r < 8; ++r) {
        int c = lane + r * 64;
        orow[c] = (v[r] - mu) * rs * gw[c] + bw[c];
    }
}

// ---------------------------------------------------------------------------
extern "C" void kernel_launch(void* const* d_in, const int* in_sizes, int n_in,
                              void* d_out, int out_size, void* d_ws, size_t ws_size,
                              hipStream_t stream)
{
    const float* q_emb  = (const float*)d_in[0];
    const float* qa_emb = (const float*)d_in[1];
    const float* Wk  = (const float*)d_in[3];
    const float* bk  = (const float*)d_in[4];
    const float* Wv  = (const float*)d_in[5];
    const float* bv  = (const float*)d_in[6];
    const float* Wo  = (const float*)d_in[7];
    const float* bo  = (const float*)d_in[8];
    const float* gam = (const float*)d_in[9];
    const float* l1g = (const float*)d_in[10];
    const float* l1b = (const float*)d_in[11];
    const float* W1  = (const float*)d_in[12];
    const float* b1  = (const float*)d_in[13];
    const float* W2  = (const float*)d_in[14];
    const float* b2  = (const float*)d_in[15];
    const float* l2g = (const float*)d_in[16];
    const float* l2b = (const float*)d_in[17];
    float* outp = (float*)d_out;

    const size_t NE = (size_t)MROWS * Dm;   // 4194304 elems per activation buf
    float* ws   = (float*)d_ws;
    float* xbuf = ws;                       // persistent x
    float* ybuf = xbuf + NE;                // persistent y
    float* t2   = ybuf + NE;                // proj / FFN output temp
    float* region = t2 + NE;                // 4*NE scratch region
    float* qb = region;                     // q (=k) heads
    float* vb = region + NE;                // v heads
    float* t1 = region + 2 * NE;            // attention output heads
    float* fb = region;                     // FFN hidden [8192, 2048] (4*NE)
    // total: 7*NE floats = 117.4 MB

    const int n = (int)NE;
    k_copy<<<n / 256, 256, 0, stream>>>(q_emb,  xbuf, n);
    k_copy<<<n / 256, 256, 0, stream>>>(qa_emb, ybuf, n);

    auto gemm = [&](const float* A, const float* W, const float* bias, float* C,
                    int M, int N, int K, bool relu) {
        dim3 grid(N / 64, M / 64);
        if (relu) k_gemm<1><<<grid, 256, 0, stream>>>(A, W, bias, C, M, N, K);
        else      k_gemm<0><<<grid, 256, 0, stream>>>(A, W, bias, C, M, N, K);
    };

    auto layer = [&](int l, int maskflag, float* Xq, float* Xv, bool apply_pos) {
        size_t wO = (size_t)l * Dm * Dm;
        // q-projection (also serves as k: query==key_ and kq_same=True)
        gemm(Xq, Wk + wO, bk + l * Dm, qb, MROWS, Dm, Dm, false);
        gemm(Xv, Wv + wO, bv + l * Dm, vb, MROWS, Dm, Dm, false);
        k_attn<<<Bsz * Hn * 32, 256, 0, stream>>>(qb, vb, t1, gam + l * Hn, maskflag);
        gemm(t1, Wo + wO, bo + l * Dm, t2, MROWS, Dm, Dm, false);
        k_ln<<<MROWS / 4, 256, 0, stream>>>(t2, Xq, l1g + l * Dm, l1b + l * Dm, Xq);
        if (apply_pos) {
            gemm(Xq, W1 + (size_t)l * Dm * DFFn, b1 + l * DFFn, fb, MROWS, DFFn, Dm, true);
            gemm(fb, W2 + (size_t)l * DFFn * Dm, b2 + l * Dm, t2, MROWS, Dm, DFFn, false);
            k_ln<<<MROWS / 4, 256, 0, stream>>>(t2, Xq, l2g + l * Dm, l2b + l * Dm, Xq);
        }
    };

    // blocks_1: self-attn on y, mask=1, FFN
    layer(0, 1, ybuf, ybuf, true);
    layer(1, 1, ybuf, ybuf, true);
    // blocks_2: (mask=1, no FFN) then (mask=0, values=y, FFN), twice
    layer(2, 1, xbuf, xbuf, false);
    layer(3, 0, xbuf, ybuf, true);
    layer(4, 1, xbuf, xbuf, false);
    layer(5, 0, xbuf, ybuf, true);

    // outputs: (x, y) concatenated
    k_copy<<<n / 256, 256, 0, stream>>>(xbuf, outp, n);
    k_copy<<<n / 256, 256, 0, stream>>>(ybuf, outp + NE, n);
}

// Round 4
// 2936.942 us; speedup vs baseline: 2.9373x; 1.9107x over previous
//
#include <hip/hip_runtime.h>
#include <hip/hip_bf16.h>

// Problem constants (AKT core): B=16, S=512, D=512, H=8, DFF=2048, NB=2, L=6
#define Bsz  16
#define Sl   512
#define Dm   512
#define Hn   8
#define DKh  64
#define DFFn 2048
#define MROWS (Bsz * Sl)      // 8192
#define NEGV (-1e32f)

typedef _Float16 f16;
typedef f16 f16x8 __attribute__((ext_vector_type(8)));
typedef f16 f16x4 __attribute__((ext_vector_type(4)));
typedef float f32x4 __attribute__((ext_vector_type(4)));

// async global->LDS, 16B per lane: lds dst = wave-uniform base + lane*16
#define GLDS16(g, l) __builtin_amdgcn_global_load_lds( \
    (const __attribute__((address_space(1))) void*)(g), \
    (__attribute__((address_space(3))) void*)(l), 16, 0, 0)

// ---------------------------------------------------------------------------
// copies
// ---------------------------------------------------------------------------
__global__ void k_copy(const float* __restrict__ in, float* __restrict__ out, int n) {
    int i = blockIdx.x * 256 + threadIdx.x;
    if (i < n) out[i] = in[i];
}
__global__ void k_copy2(const float* __restrict__ in, float* __restrict__ out,
                        f16* __restrict__ outh, int n) {
    int i = blockIdx.x * 256 + threadIdx.x;
    if (i < n) { float v = in[i]; out[i] = v; outh[i] = (f16)v; }
}

// ---------------------------------------------------------------------------
// Weight convert+transpose: W[K,N] f32 -> Wt[N,K] f16 (per layer slice z).
// lmap=1 maps output slot z -> source layer {0,1,3,5}.
// ---------------------------------------------------------------------------
__global__ __launch_bounds__(256) void k_wconv(const float* __restrict__ src,
        f16* __restrict__ dst, int K, int N, int lmap)
{
    __shared__ float T[32][36];
    int z = blockIdx.z;
    int ls = lmap ? (z < 2 ? z : 2 * z - 1) : z;
    const float* S = src + (size_t)ls * K * N;
    f16* Dt = dst + (size_t)z * K * N;
    int n0 = blockIdx.x * 32, k0 = blockIdx.y * 32;
    int t = threadIdx.x;
    int r = t >> 3, c = (t & 7) * 4;
    float4 v = *(const float4*)(S + (size_t)(k0 + r) * N + n0 + c);
    T[r][c] = v.x; T[r][c + 1] = v.y; T[r][c + 2] = v.z; T[r][c + 3] = v.w;
    __syncthreads();
    int n = t >> 3, kq = (t & 7) * 4;
    f16x4 o = { (f16)T[kq][n], (f16)T[kq + 1][n], (f16)T[kq + 2][n], (f16)T[kq + 3][n] };
    *(f16x4*)(Dt + (size_t)(n0 + n) * K + k0 + kq) = o;
}

// ---------------------------------------------------------------------------
// MFMA f16 GEMM: C[M,N] = A[M,K] @ Bt[N,K]^T + bias[N]. A,Bt f16; bias f32.
// 128x128 tile, BK=32, 4 waves (2x2 of 64x64), 16x16x32 MFMA, 4x4 tiles/wave.
// global_load_lds width=16 staging with XOR chunk swizzle (conflict-free b128).
// OUT16: write f16 (Ch), optional ReLU.
// ---------------------------------------------------------------------------
template <int RELU, int OUT16>
__global__ __launch_bounds__(256) void k_gemm(
    const f16* __restrict__ A, const f16* __restrict__ Bt,
    const float* __restrict__ bias, float* __restrict__ C, f16* __restrict__ Ch,
    int M, int N, int K)
{
    __shared__ f16 As[128 * 32];
    __shared__ f16 Bs[128 * 32];
    int tid = threadIdx.x;
    int w = tid >> 6, lane = tid & 63;
    int ln = lane & 15, rg = lane >> 4;
    int wr = w >> 1, wc = w & 1;
    int m0 = blockIdx.y * 128, n0 = blockIdx.x * 128;

    // staging: slot s -> row r=s>>2, slot-chunk s&3 holds global chunk (s&3)^((r>>1)&3)
    int s0 = tid, s1 = 256 + tid;
    int r0s = s0 >> 2, c0s = ((s0 & 3) ^ ((s0 >> 3) & 3));
    int r1s = s1 >> 2, c1s = ((s1 & 3) ^ ((s1 >> 3) & 3));

    const f16* a0 = A + (size_t)(m0 + r0s) * K + c0s * 8;
    const f16* a1 = A + (size_t)(m0 + r1s) * K + c1s * 8;
    const f16* b0 = Bt + (size_t)(n0 + r0s) * K + c0s * 8;
    const f16* b1 = Bt + (size_t)(n0 + r1s) * K + c1s * 8;
    f16* lA0 = As + (size_t)(w * 64) * 8;
    f16* lA1 = As + (size_t)(256 + w * 64) * 8;
    f16* lB0 = Bs + (size_t)(w * 64) * 8;
    f16* lB1 = Bs + (size_t)(256 + w * 64) * 8;

    int cc8 = (rg ^ ((ln >> 1) & 3)) * 8;   // swizzled chunk offset for frag reads

    f32x4 acc[4][4] = {};

    for (int kt = 0; kt < K; kt += 32) {
        __syncthreads();
        GLDS16(a0 + kt, lA0);
        GLDS16(a1 + kt, lA1);
        GLDS16(b0 + kt, lB0);
        GLDS16(b1 + kt, lB1);
        __syncthreads();

        f16x8 af[4], bf[4];
#pragma unroll
        for (int i = 0; i < 4; ++i) {
            int m = wr * 64 + i * 16 + ln;
            af[i] = *(const f16x8*)(As + m * 32 + cc8);
            int nn = wc * 64 + i * 16 + ln;
            bf[i] = *(const f16x8*)(Bs + nn * 32 + cc8);
        }
#pragma unroll
        for (int i = 0; i < 4; ++i)
#pragma unroll
            for (int j = 0; j < 4; ++j)
                acc[i][j] = __builtin_amdgcn_mfma_f32_16x16x32_f16(af[i], bf[j], acc[i][j], 0, 0, 0);
    }

#pragma unroll
    for (int j = 0; j < 4; ++j) {
        int col = n0 + wc * 64 + j * 16 + ln;
        float bj = bias[col];
#pragma unroll
        for (int i = 0; i < 4; ++i) {
            int rb = m0 + wr * 64 + i * 16 + rg * 4;
#pragma unroll
            for (int r = 0; r < 4; ++r) {
                float v = acc[i][j][r] + bj;
                if (RELU) v = fmaxf(v, 0.f);
                if (OUT16) Ch[(size_t)(rb + r) * N + col] = (f16)v;
                else       C [(size_t)(rb + r) * N + col] = v;
            }
        }
    }
}

// ---------------------------------------------------------------------------
// AKT attention, LDS-tiled. One block per (b, h, 16-row i-tile).
// Conflict-free staging (j = lane for K-transpose), 3 blocks/CU LDS budget,
// vectorized phase-3. Output written as f16 (feeds Wo MFMA GEMM).
// ---------------------------------------------------------------------------
__global__ __launch_bounds__(256) void k_attn(
    const float* __restrict__ Q, const float* __restrict__ V,
    f16* __restrict__ O, const float* __restrict__ gam, int maskflag)
{
    __shared__ float Sc[16][512];      // scores/attn, rows wave-private
    __shared__ float Qt[64][16];       // Q tile transposed [d][row]
    __shared__ float KV[64 * 68];      // K tile [d*64+j] / V tile [j*68+d]

    int tid = threadIdx.x;
    int w = tid >> 6, lane = tid & 63;
    int tile = blockIdx.x & 31;
    int bh   = blockIdx.x >> 5;
    int b = bh >> 3, h = bh & 7;
    int i0 = tile * 16;
    int jtc = (i0 + 16 + 63) >> 6;

    const float* Qbase = Q + (size_t)b * Sl * Dm + h * DKh;
    const float* Vbase = V + (size_t)b * Sl * Dm + h * DKh;

    float gm = gam[h];
    float g = -((gm > 20.f) ? gm : log1pf(__expf(gm)));   // -softplus(gamma)

    {   // stage Q tile transposed
        int row = tid >> 4;
        int dq  = (tid & 15) * 4;
        float4 qv = *(const float4*)(Qbase + (size_t)(i0 + row) * Dm + dq);
        Qt[dq + 0][row] = qv.x; Qt[dq + 1][row] = qv.y;
        Qt[dq + 2][row] = qv.z; Qt[dq + 3][row] = qv.w;
    }
    __syncthreads();

    int rg = lane >> 4;        // k-dim split group
    int jj = lane & 15;        // j group (4 cols)
    int r0 = w * 4;

    // ---- Phase 1: scores -----------------------------------------------
    int jK = tid & 63;         // K staging: j = lane index -> conflict-free
    int dK = (tid >> 6) * 16;  // wave picks d-block
    for (int jt = 0; jt < jtc; ++jt) {
        int j0 = jt * 64;
        {
            const float* src = Qbase + (size_t)(j0 + jK) * Dm + dK;
            float4 k0v = *(const float4*)(src + 0);
            float4 k1v = *(const float4*)(src + 4);
            float4 k2v = *(const float4*)(src + 8);
            float4 k3v = *(const float4*)(src + 12);
            float* kt = KV + jK;
            kt[(dK + 0) * 64] = k0v.x; kt[(dK + 1) * 64] = k0v.y;
            kt[(dK + 2) * 64] = k0v.z; kt[(dK + 3) * 64] = k0v.w;
            kt[(dK + 4) * 64] = k1v.x; kt[(dK + 5) * 64] = k1v.y;
            kt[(dK + 6) * 64] = k1v.z; kt[(dK + 7) * 64] = k1v.w;
            kt[(dK + 8) * 64] = k2v.x; kt[(dK + 9) * 64] = k2v.y;
            kt[(dK +10) * 64] = k2v.z; kt[(dK +11) * 64] = k2v.w;
            kt[(dK +12) * 64] = k3v.x; kt[(dK +13) * 64] = k3v.y;
            kt[(dK +14) * 64] = k3v.z; kt[(dK +15) * 64] = k3v.w;
        }
        __syncthreads();

        float acc[4][4] = {};
#pragma unroll
        for (int dd = 0; dd < 16; ++dd) {
            int d = rg * 16 + dd;
            float4 qv = *(const float4*)&Qt[d][r0];
            float4 kv = *(const float4*)&KV[d * 64 + jj * 4];
            acc[0][0] += qv.x * kv.x; acc[0][1] += qv.x * kv.y; acc[0][2] += qv.x * kv.z; acc[0][3] += qv.x * kv.w;
            acc[1][0] += qv.y * kv.x; acc[1][1] += qv.y * kv.y; acc[1][2] += qv.y * kv.z; acc[1][3] += qv.y * kv.w;
            acc[2][0] += qv.z * kv.x; acc[2][1] += qv.z * kv.y; acc[2][2] += qv.z * kv.z; acc[2][3] += qv.z * kv.w;
            acc[3][0] += qv.w * kv.x; acc[3][1] += qv.w * kv.y; acc[3][2] += qv.w * kv.z; acc[3][3] += qv.w * kv.w;
        }
#pragma unroll
        for (int ri = 0; ri < 4; ++ri)
#pragma unroll
            for (int cj = 0; cj < 4; ++cj) {
                float v = acc[ri][cj];
                v += __shfl_xor(v, 16);
                v += __shfl_xor(v, 32);
                acc[ri][cj] = v;
            }
        if (rg == 0) {
#pragma unroll
            for (int ri = 0; ri < 4; ++ri) {
                float4 o = make_float4(acc[ri][0], acc[ri][1], acc[ri][2], acc[ri][3]);
                *(float4*)&Sc[r0 + ri][j0 + jj * 4] = o;
            }
        }
        __syncthreads();
    }

    // ---- Phase 2: softmax -> cumsum -> decay -> softmax (wave-private) --
    for (int q = 0; q < 4; ++q) {
        int r = r0 + q;
        int i = i0 + r;
        int jmax = maskflag ? i : (i - 1);

        float4 s0 = *(float4*)&Sc[r][lane * 8];
        float4 s1 = *(float4*)&Sc[r][lane * 8 + 4];
        float s[8] = {s0.x, s0.y, s0.z, s0.w, s1.x, s1.y, s1.z, s1.w};
#pragma unroll
        for (int k = 0; k < 8; ++k) {
            int j = lane * 8 + k;
            s[k] = (j <= jmax) ? s[k] * 0.125f : NEGV;
        }
        float m = s[0];
#pragma unroll
        for (int k = 1; k < 8; ++k) m = fmaxf(m, s[k]);
#pragma unroll
        for (int off = 32; off >= 1; off >>= 1) m = fmaxf(m, __shfl_xor(m, off));
        float p[8], Z = 0.f;
#pragma unroll
        for (int k = 0; k < 8; ++k) { p[k] = __expf(s[k] - m); Z += p[k]; }
#pragma unroll
        for (int off = 32; off >= 1; off >>= 1) Z += __shfl_xor(Z, off);
        float inv = 1.f / Z;

        float cs[8], run = 0.f;
#pragma unroll
        for (int k = 0; k < 8; ++k) {
            int j = lane * 8 + k;
            float pm = (j <= jmax) ? p[k] * inv : 0.f;
            run += pm;
            cs[k] = run;
        }
        float sl = run;
#pragma unroll
        for (int off = 1; off < 64; off <<= 1) {
            float nv = __shfl_up(sl, off);
            if (lane >= off) sl += nv;
        }
        float excl = sl - run;
        float tot = __shfl(sl, 63);

#pragma unroll
        for (int k = 0; k < 8; ++k) {
            int j = lane * 8 + k;
            float dc = excl + cs[k];
            float pos = fabsf((float)(i - j));
            float dd = fmaxf((tot - dc) * pos, 0.f);
            float te = __expf(sqrtf(dd) * g);
            te = fminf(fmaxf(te, 1e-5f), 1e5f);
            s[k] = (j <= jmax) ? s[k] * te : NEGV;
        }

        m = s[0];
#pragma unroll
        for (int k = 1; k < 8; ++k) m = fmaxf(m, s[k]);
#pragma unroll
        for (int off = 32; off >= 1; off >>= 1) m = fmaxf(m, __shfl_xor(m, off));
        Z = 0.f;
#pragma unroll
        for (int k = 0; k < 8; ++k) { p[k] = __expf(s[k] - m); Z += p[k]; }
#pragma unroll
        for (int off = 32; off >= 1; off >>= 1) Z += __shfl_xor(Z, off);
        inv = 1.f / Z;

        int zp = (maskflag == 0) && (i == 0);
        float4 a0, a1;
        a0.x = zp ? 0.f : p[0] * inv; a0.y = zp ? 0.f : p[1] * inv;
        a0.z = zp ? 0.f : p[2] * inv; a0.w = zp ? 0.f : p[3] * inv;
        a1.x = zp ? 0.f : p[4] * inv; a1.y = zp ? 0.f : p[5] * inv;
        a1.z = zp ? 0.f : p[6] * inv; a1.w = zp ? 0.f : p[7] * inv;
        *(float4*)&Sc[r][lane * 8]     = a0;
        *(float4*)&Sc[r][lane * 8 + 4] = a1;
    }

    // ---- Phase 3: O = attn @ V (vectorized) ----------------------------
    int rr = lane >> 4, dg = lane & 15;
    float4 oacc = make_float4(0.f, 0.f, 0.f, 0.f);
    int r = r0 + rr;

    for (int jt = 0; jt < jtc; ++jt) {
        int j0 = jt * 64;
        __syncthreads();
        {   // stage V tile row-major: KV[j*68 + d]
            int jr = tid >> 2;
            int dq = (tid & 3) * 16;
            const float* src = Vbase + (size_t)(j0 + jr) * Dm + dq;
            float4 v0 = *(const float4*)(src + 0);
            float4 v1 = *(const float4*)(src + 4);
            float4 v2 = *(const float4*)(src + 8);
            float4 v3 = *(const float4*)(src + 12);
            float* vs = KV + jr * 68 + dq;
            *(float4*)(vs + 0)  = v0;
            *(float4*)(vs + 4)  = v1;
            *(float4*)(vs + 8)  = v2;
            *(float4*)(vs + 12) = v3;
        }
        __syncthreads();
#pragma unroll 4
        for (int j4 = 0; j4 < 16; ++j4) {
            float4 a = *(const float4*)&Sc[r][j0 + j4 * 4];
            const float* vrow = KV + (j4 * 4) * 68 + dg * 4;
            float4 v0 = *(const float4*)(vrow);
            float4 v1 = *(const float4*)(vrow + 68);
            float4 v2 = *(const float4*)(vrow + 136);
            float4 v3 = *(const float4*)(vrow + 204);
            oacc.x += a.x * v0.x + a.y * v1.x + a.z * v2.x + a.w * v3.x;
            oacc.y += a.x * v0.y + a.y * v1.y + a.z * v2.y + a.w * v3.y;
            oacc.z += a.x * v0.z + a.y * v1.z + a.z * v2.z + a.w * v3.z;
            oacc.w += a.x * v0.w + a.y * v1.w + a.z * v2.w + a.w * v3.w;
        }
    }

    f16* dst = O + ((size_t)b * Sl + i0 + r) * Dm + h * DKh + dg * 4;
    f16x4 o4 = { (f16)oacc.x, (f16)oacc.y, (f16)oacc.z, (f16)oacc.w };
    *(f16x4*)dst = o4;
}

// ---------------------------------------------------------------------------
// Residual + LayerNorm: Out = LN(Xn + Rr)*g + b, dual f32+f16 output.
// ---------------------------------------------------------------------------
__global__ __launch_bounds__(256) void k_ln(
    const float* __restrict__ Xn, const float* __restrict__ Rr,
    const float* __restrict__ gw, const float* __restrict__ bw,
    float* __restrict__ Out, f16* __restrict__ Outh)
{
    int tid = threadIdx.x;
    int w = tid >> 6, lane = tid & 63;
    int row = blockIdx.x * 4 + w;
    const float* xr = Xn + (size_t)row * Dm;
    const float* rr = Rr + (size_t)row * Dm;
    float v[8], sum = 0.f;
#pragma unroll
    for (int r = 0; r < 8; ++r) {
        int c = lane + r * 64;
        v[r] = xr[c] + rr[c];
        sum += v[r];
    }
#pragma unroll
    for (int off = 32; off >= 1; off >>= 1) sum += __shfl_xor(sum, off);
    float mu = sum * (1.f / 512.f);
    float var = 0.f;
#pragma unroll
    for (int r = 0; r < 8; ++r) { float d = v[r] - mu; var += d * d; }
#pragma unroll
    for (int off = 32; off >= 1; off >>= 1) var += __shfl_xor(var, off);
    float rs = rsqrtf(var * (1.f / 512.f) + 1e-5f);
    float* orow = Out + (size_t)row * Dm;
    f16* ohrow = Outh + (size_t)row * Dm;
#pragma unroll
    for (int r = 0; r < 8; ++r) {
        int c = lane + r * 64;
        float val = (v[r] - mu) * rs * gw[c] + bw[c];
        orow[c] = val;
        ohrow[c] = (f16)val;
    }
}

// ---------------------------------------------------------------------------
extern "C" void kernel_launch(void* const* d_in, const int* in_sizes, int n_in,
                              void* d_out, int out_size, void* d_ws, size_t ws_size,
                              hipStream_t stream)
{
    const float* q_emb  = (const float*)d_in[0];
    const float* qa_emb = (const float*)d_in[1];
    const float* Wk  = (const float*)d_in[3];
    const float* bk  = (const float*)d_in[4];
    const float* Wv  = (const float*)d_in[5];
    const float* bv  = (const float*)d_in[6];
    const float* Wo  = (const float*)d_in[7];
    const float* bo  = (const float*)d_in[8];
    const float* gam = (const float*)d_in[9];
    const float* l1g = (const float*)d_in[10];
    const float* l1b = (const float*)d_in[11];
    const float* W1  = (const float*)d_in[12];
    const float* b1  = (const float*)d_in[13];
    const float* W2  = (const float*)d_in[14];
    const float* b2  = (const float*)d_in[15];
    const float* l2g = (const float*)d_in[16];
    const float* l2b = (const float*)d_in[17];
    float* outp = (float*)d_out;

    const size_t NE  = (size_t)MROWS * Dm;    // 4194304
    const size_t WDD = (size_t)Dm * Dm;       // 262144
    const size_t WDF = (size_t)Dm * DFFn;     // 1048576

    float* xbuf = (float*)d_ws;               // NE
    float* ybuf = xbuf + NE;                  // NE
    float* t2   = ybuf + NE;                  // NE (doubles as qb)
    float* vb   = t2 + NE;                    // NE
    f16* xh  = (f16*)(vb + NE);               // NE
    f16* yh  = xh + NE;                       // NE
    f16* t1h = yh + NE;                       // NE
    f16* fbh = t1h + NE;                      // 4*NE (FFN hidden, f16)
    f16* wkh = fbh + 4 * NE;                  // 6*WDD
    f16* wvh = wkh + 6 * WDD;
    f16* woh = wvh + 6 * WDD;
    f16* w1h = woh + 6 * WDD;                 // 4*WDF (slots 0,1,3,5)
    f16* w2h = w1h + 4 * WDF;                 // 4*WDF
    // total ~152 MB

    // ---- per-call weight convert+transpose (f32 [K,N] -> f16 [N,K]) ----
    k_wconv<<<dim3(Dm / 32, Dm / 32, 6), 256, 0, stream>>>(Wk, wkh, Dm, Dm, 0);
    k_wconv<<<dim3(Dm / 32, Dm / 32, 6), 256, 0, stream>>>(Wv, wvh, Dm, Dm, 0);
    k_wconv<<<dim3(Dm / 32, Dm / 32, 6), 256, 0, stream>>>(Wo, woh, Dm, Dm, 0);
    k_wconv<<<dim3(DFFn / 32, Dm / 32, 4), 256, 0, stream>>>(W1, w1h, Dm, DFFn, 1);
    k_wconv<<<dim3(Dm / 32, DFFn / 32, 4), 256, 0, stream>>>(W2, w2h, DFFn, Dm, 1);

    const int n = (int)NE;
    k_copy2<<<n / 256, 256, 0, stream>>>(q_emb,  xbuf, xh, n);
    k_copy2<<<n / 256, 256, 0, stream>>>(qa_emb, ybuf, yh, n);

    auto gemm32 = [&](const f16* A, const f16* Bt, const float* bias, float* C,
                      int M, int N, int K) {
        k_gemm<0, 0><<<dim3(N / 128, M / 128), 256, 0, stream>>>(A, Bt, bias, C, nullptr, M, N, K);
    };

    auto layer = [&](int l, int maskflag, float* Xq, f16* Xqh, f16* Xvh, bool apply_pos) {
        const f16* wkt = wkh + (size_t)l * WDD;
        const f16* wvt = wvh + (size_t)l * WDD;
        const f16* wot = woh + (size_t)l * WDD;
        gemm32(Xqh, wkt, bk + l * Dm, t2, MROWS, Dm, Dm);      // q (=k) heads
        gemm32(Xvh, wvt, bv + l * Dm, vb, MROWS, Dm, Dm);      // v heads
        k_attn<<<Bsz * Hn * 32, 256, 0, stream>>>(t2, vb, t1h, gam + l * Hn, maskflag);
        gemm32(t1h, wot, bo + l * Dm, vb, MROWS, Dm, Dm);      // out proj -> vb
        k_ln<<<MROWS / 4, 256, 0, stream>>>(vb, Xq, l1g + l * Dm, l1b + l * Dm, Xq, Xqh);
        if (apply_pos) {
            int sl = (l < 2) ? l : ((l + 1) >> 1);
            k_gemm<1, 1><<<dim3(DFFn / 128, MROWS / 128), 256, 0, stream>>>(
                Xqh, w1h + (size_t)sl * WDF, b1 + l * DFFn, nullptr, fbh, MROWS, DFFn, Dm);
            k_gemm<0, 0><<<dim3(Dm / 128, MROWS / 128), 256, 0, stream>>>(
                fbh, w2h + (size_t)sl * WDF, b2 + l * Dm, t2, nullptr, MROWS, Dm, DFFn);
            k_ln<<<MROWS / 4, 256, 0, stream>>>(t2, Xq, l2g + l * Dm, l2b + l * Dm, Xq, Xqh);
        }
    };

    // blocks_1: self-attn on y, mask=1, FFN
    layer(0, 1, ybuf, yh, yh, true);
    layer(1, 1, ybuf, yh, yh, true);
    // blocks_2: (mask=1, no FFN) then (mask=0, values=y, FFN), twice
    layer(2, 1, xbuf, xh, xh, false);
    layer(3, 0, xbuf, xh, yh, true);
    layer(4, 1, xbuf, xh, xh, false);
    layer(5, 0, xbuf, xh, yh, true);

    // outputs: (x, y) concatenated, f32
    k_copy<<<n / 256, 256, 0, stream>>>(xbuf, outp, n);
    k_copy<<<n / 256, 256, 0, stream>>>(ybuf, outp + NE, n);
}

// Round 5
// 1499.733 us; speedup vs baseline: 5.7521x; 1.9583x over previous
//
#include <hip/hip_runtime.h>
#include <hip/hip_bf16.h>

// Problem constants (AKT core): B=16, S=512, D=512, H=8, DFF=2048, NB=2, L=6
#define Bsz  16
#define Sl   512
#define Dm   512
#define Hn   8
#define DKh  64
#define DFFn 2048
#define MROWS (Bsz * Sl)      // 8192
#define NEGV (-1e32f)

typedef _Float16 f16;
typedef f16 f16x8 __attribute__((ext_vector_type(8)));
typedef f16 f16x4 __attribute__((ext_vector_type(4)));
typedef float f32x4 __attribute__((ext_vector_type(4)));

// async global->LDS, 16B per lane: lds dst = wave-uniform base + lane*16
#define GLDS16(g, l) __builtin_amdgcn_global_load_lds( \
    (const __attribute__((address_space(1))) void*)(g), \
    (__attribute__((address_space(3))) void*)(l), 16, 0, 0)

// ---------------------------------------------------------------------------
// copies
// ---------------------------------------------------------------------------
__global__ void k_copy(const float* __restrict__ in, float* __restrict__ out, int n) {
    int i = blockIdx.x * 256 + threadIdx.x;
    if (i < n) out[i] = in[i];
}
__global__ void k_copy2(const float* __restrict__ in, float* __restrict__ out,
                        f16* __restrict__ outh, int n) {
    int i = blockIdx.x * 256 + threadIdx.x;
    if (i < n) { float v = in[i]; out[i] = v; outh[i] = (f16)v; }
}

// ---------------------------------------------------------------------------
// Weight convert+transpose: W[K,N] f32 -> Wt[N,K] f16 (per layer slice z).
// lmap=1 maps output slot z -> source layer {0,1,3,5}.
// ---------------------------------------------------------------------------
__global__ __launch_bounds__(256) void k_wconv(const float* __restrict__ src,
        f16* __restrict__ dst, int K, int N, int lmap)
{
    __shared__ float T[32][36];
    int z = blockIdx.z;
    int ls = lmap ? (z < 2 ? z : 2 * z - 1) : z;
    const float* S = src + (size_t)ls * K * N;
    f16* Dt = dst + (size_t)z * K * N;
    int n0 = blockIdx.x * 32, k0 = blockIdx.y * 32;
    int t = threadIdx.x;
    int r = t >> 3, c = (t & 7) * 4;
    float4 v = *(const float4*)(S + (size_t)(k0 + r) * N + n0 + c);
    T[r][c] = v.x; T[r][c + 1] = v.y; T[r][c + 2] = v.z; T[r][c + 3] = v.w;
    __syncthreads();
    int n = t >> 3, kq = (t & 7) * 4;
    f16x4 o = { (f16)T[kq][n], (f16)T[kq + 1][n], (f16)T[kq + 2][n], (f16)T[kq + 3][n] };
    *(f16x4*)(Dt + (size_t)(n0 + n) * K + k0 + kq) = o;
}

// ---------------------------------------------------------------------------
// V transpose per head: vh [B*S, 512] f16 -> vt [128 bh][64 d][512 s] f16
// ---------------------------------------------------------------------------
__global__ __launch_bounds__(256) void k_vt(const f16* __restrict__ vh,
                                            f16* __restrict__ vt)
{
    __shared__ f16 T[64][80];
    int s0 = (blockIdx.x & 7) * 64;
    int bh = blockIdx.x >> 3;
    int b = bh >> 3, h = bh & 7;
    int tid = threadIdx.x;
    int row = tid >> 2, ck = (tid & 3) * 16;
    const f16* src = vh + ((size_t)b * Sl + s0 + row) * Dm + h * DKh + ck;
    *(f16x8*)&T[row][ck]     = *(const f16x8*)(src);
    *(f16x8*)&T[row][ck + 8] = *(const f16x8*)(src + 8);
    __syncthreads();
    int d = tid >> 2, sg = (tid & 3) * 16;
    f16 tmp[16];
#pragma unroll
    for (int t = 0; t < 16; ++t) tmp[t] = T[sg + t][d];
    f16* dst = vt + ((size_t)bh * 64 + d) * 512 + s0 + sg;
    *(f16x8*)(dst)     = *(f16x8*)(tmp);
    *(f16x8*)(dst + 8) = *(f16x8*)(tmp + 8);
}

// ---------------------------------------------------------------------------
// MFMA f16 GEMM: C[M,N] = A[M,K] @ Bt[N,K]^T + bias[N]. A,Bt f16; bias f32.
// 128x128 tile, BK=32, 4 waves (2x2 of 64x64), 16x16x32 MFMA, 4x4 tiles/wave.
// ---------------------------------------------------------------------------
template <int RELU, int OUT16>
__global__ __launch_bounds__(256) void k_gemm(
    const f16* __restrict__ A, const f16* __restrict__ Bt,
    const float* __restrict__ bias, float* __restrict__ C, f16* __restrict__ Ch,
    int M, int N, int K)
{
    __shared__ f16 As[128 * 32];
    __shared__ f16 Bs[128 * 32];
    int tid = threadIdx.x;
    int w = tid >> 6, lane = tid & 63;
    int ln = lane & 15, rg = lane >> 4;
    int wr = w >> 1, wc = w & 1;
    int m0 = blockIdx.y * 128, n0 = blockIdx.x * 128;

    int s0 = tid, s1 = 256 + tid;
    int r0s = s0 >> 2, c0s = ((s0 & 3) ^ ((s0 >> 3) & 3));
    int r1s = s1 >> 2, c1s = ((s1 & 3) ^ ((s1 >> 3) & 3));

    const f16* a0 = A + (size_t)(m0 + r0s) * K + c0s * 8;
    const f16* a1 = A + (size_t)(m0 + r1s) * K + c1s * 8;
    const f16* b0 = Bt + (size_t)(n0 + r0s) * K + c0s * 8;
    const f16* b1 = Bt + (size_t)(n0 + r1s) * K + c1s * 8;
    f16* lA0 = As + (size_t)(w * 64) * 8;
    f16* lA1 = As + (size_t)(256 + w * 64) * 8;
    f16* lB0 = Bs + (size_t)(w * 64) * 8;
    f16* lB1 = Bs + (size_t)(256 + w * 64) * 8;

    int cc8 = (rg ^ ((ln >> 1) & 3)) * 8;

    f32x4 acc[4][4] = {};

    for (int kt = 0; kt < K; kt += 32) {
        __syncthreads();
        GLDS16(a0 + kt, lA0);
        GLDS16(a1 + kt, lA1);
        GLDS16(b0 + kt, lB0);
        GLDS16(b1 + kt, lB1);
        __syncthreads();

        f16x8 af[4], bf[4];
#pragma unroll
        for (int i = 0; i < 4; ++i) {
            int m = wr * 64 + i * 16 + ln;
            af[i] = *(const f16x8*)(As + m * 32 + cc8);
            int nn = wc * 64 + i * 16 + ln;
            bf[i] = *(const f16x8*)(Bs + nn * 32 + cc8);
        }
#pragma unroll
        for (int i = 0; i < 4; ++i)
#pragma unroll
            for (int j = 0; j < 4; ++j)
                acc[i][j] = __builtin_amdgcn_mfma_f32_16x16x32_f16(af[i], bf[j], acc[i][j], 0, 0, 0);
    }

#pragma unroll
    for (int j = 0; j < 4; ++j) {
        int col = n0 + wc * 64 + j * 16 + ln;
        float bj = bias[col];
#pragma unroll
        for (int i = 0; i < 4; ++i) {
            int rb = m0 + wr * 64 + i * 16 + rg * 4;
#pragma unroll
            for (int r = 0; r < 4; ++r) {
                float v = acc[i][j][r] + bj;
                if (RELU) v = fmaxf(v, 0.f);
                if (OUT16) Ch[(size_t)(rb + r) * N + col] = (f16)v;
                else       C [(size_t)(rb + r) * N + col] = v;
            }
        }
    }
}

// ---------------------------------------------------------------------------
// AKT attention, MFMA. One block per (b, h, 16-row i-tile), 4 waves.
// Phase 1: S = Q K^T via mfma 16x16x32_f16, frags direct from global (qh),
//          j-tiles round-robin across waves, C-frags -> LDS Sc f32.
// Phase 2: per-row softmax/cumsum/decay/softmax (wave w owns rows w*4..+3),
//          writes P f16 into XOR-swizzled Ph.
// Phase 3: O = P V via mfma; wave w owns d-block nb=w; A from Ph (swizzled),
//          B from vt global. Two barriers total.
// ---------------------------------------------------------------------------
__global__ __launch_bounds__(256) void k_attn(
    const f16* __restrict__ Qh, const f16* __restrict__ VT,
    f16* __restrict__ O, const float* __restrict__ gam, int maskflag)
{
    __shared__ float Sc[16][516];
    __shared__ f16 Ph[16 * 512];

    int tid = threadIdx.x;
    int w = tid >> 6, lane = tid & 63;
    int ln = lane & 15, rg = lane >> 4;
    int tile = blockIdx.x & 31;
    int bh = blockIdx.x >> 5;
    int b = bh >> 3, h = bh & 7;
    int i0 = tile * 16;
    int jtc = (tile >> 2) + 1;

    const f16* Qbase = Qh + ((size_t)b * Sl) * Dm + h * DKh;

    float gm = gam[h];
    float g = -((gm > 20.f) ? gm : log1pf(__expf(gm)));   // -softplus(gamma)

    // A-frags: Q rows i0..i0+15 (A[m=ln][k=rg*8+t]), reused across j-tiles
    f16x8 aq0 = *(const f16x8*)(Qbase + (size_t)(i0 + ln) * Dm + rg * 8);
    f16x8 aq1 = *(const f16x8*)(Qbase + (size_t)(i0 + ln) * Dm + 32 + rg * 8);

    // ---- Phase 1: scores ------------------------------------------------
    for (int jt = w; jt < jtc; jt += 4) {
        int j0 = jt * 64;
#pragma unroll
        for (int nb = 0; nb < 4; ++nb) {
            const f16* kb = Qbase + (size_t)(j0 + nb * 16 + ln) * Dm + rg * 8;
            f16x8 b0 = *(const f16x8*)(kb);
            f16x8 b1 = *(const f16x8*)(kb + 32);
            f32x4 c = {};
            c = __builtin_amdgcn_mfma_f32_16x16x32_f16(aq0, b0, c, 0, 0, 0);
            c = __builtin_amdgcn_mfma_f32_16x16x32_f16(aq1, b1, c, 0, 0, 0);
#pragma unroll
            for (int r = 0; r < 4; ++r)
                Sc[rg * 4 + r][j0 + nb * 16 + ln] = c[r];
        }
    }
    __syncthreads();

    // ---- Phase 2: softmax -> cumsum -> decay -> softmax -----------------
    for (int q = 0; q < 4; ++q) {
        int r = w * 4 + q;
        int i = i0 + r;
        int jmax = maskflag ? i : (i - 1);

        float4 s0 = *(float4*)&Sc[r][lane * 8];
        float4 s1 = *(float4*)&Sc[r][lane * 8 + 4];
        float s[8] = {s0.x, s0.y, s0.z, s0.w, s1.x, s1.y, s1.z, s1.w};
#pragma unroll
        for (int k = 0; k < 8; ++k) {
            int j = lane * 8 + k;
            s[k] = (j <= jmax) ? s[k] * 0.125f : NEGV;
        }
        float m = s[0];
#pragma unroll
        for (int k = 1; k < 8; ++k) m = fmaxf(m, s[k]);
#pragma unroll
        for (int off = 32; off >= 1; off >>= 1) m = fmaxf(m, __shfl_xor(m, off));
        float p[8], Z = 0.f;
#pragma unroll
        for (int k = 0; k < 8; ++k) { p[k] = __expf(s[k] - m); Z += p[k]; }
#pragma unroll
        for (int off = 32; off >= 1; off >>= 1) Z += __shfl_xor(Z, off);
        float inv = 1.f / Z;

        float cs[8], run = 0.f;
#pragma unroll
        for (int k = 0; k < 8; ++k) {
            int j = lane * 8 + k;
            float pm = (j <= jmax) ? p[k] * inv : 0.f;
            run += pm;
            cs[k] = run;
        }
        float sl = run;
#pragma unroll
        for (int off = 1; off < 64; off <<= 1) {
            float nv = __shfl_up(sl, off);
            if (lane >= off) sl += nv;
        }
        float excl = sl - run;
        float tot = __shfl(sl, 63);

#pragma unroll
        for (int k = 0; k < 8; ++k) {
            int j = lane * 8 + k;
            float dc = excl + cs[k];
            float pos = fabsf((float)(i - j));
            float dd = fmaxf((tot - dc) * pos, 0.f);
            float te = __expf(sqrtf(dd) * g);
            te = fminf(fmaxf(te, 1e-5f), 1e5f);
            s[k] = (j <= jmax) ? s[k] * te : NEGV;
        }

        m = s[0];
#pragma unroll
        for (int k = 1; k < 8; ++k) m = fmaxf(m, s[k]);
#pragma unroll
        for (int off = 32; off >= 1; off >>= 1) m = fmaxf(m, __shfl_xor(m, off));
        Z = 0.f;
#pragma unroll
        for (int k = 0; k < 8; ++k) { p[k] = __expf(s[k] - m); Z += p[k]; }
#pragma unroll
        for (int off = 32; off >= 1; off >>= 1) Z += __shfl_xor(Z, off);
        inv = 1.f / Z;

        int zp = (maskflag == 0) && (i == 0);
        float a[8];
#pragma unroll
        for (int k = 0; k < 8; ++k) a[k] = zp ? 0.f : p[k] * inv;

        // write P f16, chunk c=lane, slot low3 ^= (r&7)  -> conflict-free
        int slot = (lane & ~7) | ((lane & 7) ^ (r & 7));
        f16x8 o8 = { (f16)a[0], (f16)a[1], (f16)a[2], (f16)a[3],
                     (f16)a[4], (f16)a[5], (f16)a[6], (f16)a[7] };
        *(f16x8*)(Ph + r * 512 + slot * 8) = o8;
    }
    __syncthreads();

    // ---- Phase 3: O = P @ V, wave w owns d-block nb=w -------------------
    f32x4 oa = {};
    for (int jt = 0; jt < jtc; ++jt) {
        int j0 = jt * 64;
#pragma unroll
        for (int ks = 0; ks < 2; ++ks) {
            int c = jt * 8 + ks * 4 + rg;
            int slot = (c & ~7) | ((c & 7) ^ (ln & 7));
            f16x8 ap = *(const f16x8*)(Ph + ln * 512 + slot * 8);
            const f16* vb_ = VT + ((size_t)bh * 64 + w * 16 + ln) * 512
                             + j0 + ks * 32 + rg * 8;
            f16x8 bv = *(const f16x8*)vb_;
            oa = __builtin_amdgcn_mfma_f32_16x16x32_f16(ap, bv, oa, 0, 0, 0);
        }
    }
    f16* ob = O + ((size_t)b * Sl + i0 + rg * 4) * Dm + h * DKh + w * 16 + ln;
#pragma unroll
    for (int r = 0; r < 4; ++r)
        ob[(size_t)r * Dm] = (f16)oa[r];
}

// ---------------------------------------------------------------------------
// Residual + LayerNorm: Out = LN(Xn + Rr)*g + b, dual f32+f16 output.
// ---------------------------------------------------------------------------
__global__ __launch_bounds__(256) void k_ln(
    const float* __restrict__ Xn, const float* __restrict__ Rr,
    const float* __restrict__ gw, const float* __restrict__ bw,
    float* __restrict__ Out, f16* __restrict__ Outh)
{
    int tid = threadIdx.x;
    int w = tid >> 6, lane = tid & 63;
    int row = blockIdx.x * 4 + w;
    const float* xr = Xn + (size_t)row * Dm;
    const float* rr = Rr + (size_t)row * Dm;
    float v[8], sum = 0.f;
#pragma unroll
    for (int r = 0; r < 8; ++r) {
        int c = lane + r * 64;
        v[r] = xr[c] + rr[c];
        sum += v[r];
    }
#pragma unroll
    for (int off = 32; off >= 1; off >>= 1) sum += __shfl_xor(sum, off);
    float mu = sum * (1.f / 512.f);
    float var = 0.f;
#pragma unroll
    for (int r = 0; r < 8; ++r) { float d = v[r] - mu; var += d * d; }
#pragma unroll
    for (int off = 32; off >= 1; off >>= 1) var += __shfl_xor(var, off);
    float rs = rsqrtf(var * (1.f / 512.f) + 1e-5f);
    float* orow = Out + (size_t)row * Dm;
    f16* ohrow = Outh + (size_t)row * Dm;
#pragma unroll
    for (int r = 0; r < 8; ++r) {
        int c = lane + r * 64;
        float val = (v[r] - mu) * rs * gw[c] + bw[c];
        orow[c] = val;
        ohrow[c] = (f16)val;
    }
}

// ---------------------------------------------------------------------------
extern "C" void kernel_launch(void* const* d_in, const int* in_sizes, int n_in,
                              void* d_out, int out_size, void* d_ws, size_t ws_size,
                              hipStream_t stream)
{
    const float* q_emb  = (const float*)d_in[0];
    const float* qa_emb = (const float*)d_in[1];
    const float* Wk  = (const float*)d_in[3];
    const float* bk  = (const float*)d_in[4];
    const float* Wv  = (const float*)d_in[5];
    const float* bv  = (const float*)d_in[6];
    const float* Wo  = (const float*)d_in[7];
    const float* bo  = (const float*)d_in[8];
    const float* gam = (const float*)d_in[9];
    const float* l1g = (const float*)d_in[10];
    const float* l1b = (const float*)d_in[11];
    const float* W1  = (const float*)d_in[12];
    const float* b1  = (const float*)d_in[13];
    const float* W2  = (const float*)d_in[14];
    const float* b2  = (const float*)d_in[15];
    const float* l2g = (const float*)d_in[16];
    const float* l2b = (const float*)d_in[17];
    float* outp = (float*)d_out;

    const size_t NE  = (size_t)MROWS * Dm;    // 4194304
    const size_t WDD = (size_t)Dm * Dm;
    const size_t WDF = (size_t)Dm * DFFn;

    float* xbuf = (float*)d_ws;               // NE f32
    float* ybuf = xbuf + NE;                  // NE f32
    float* t2   = ybuf + NE;                  // NE f32 (LN input temp)
    f16* xh  = (f16*)(t2 + NE);               // NE
    f16* yh  = xh + NE;                       // NE
    f16* R   = yh + NE;                       // 4*NE f16 region
    f16* qh  = R;                             // q(=k) heads f16
    f16* vh  = R + NE;                        // v heads f16
    f16* vt  = R + 2 * NE;                    // v transposed per head
    f16* t1h = R + 3 * NE;                    // attention output f16
    f16* fbh = R;                             // FFN hidden (aliases R, 4*NE)
    f16* wkh = R + 4 * NE;                    // weights f16
    f16* wvh = wkh + 6 * WDD;
    f16* woh = wvh + 6 * WDD;
    f16* w1h = woh + 6 * WDD;                 // slots 0,1,3,5
    f16* w2h = w1h + 4 * WDF;

    // ---- per-call weight convert+transpose (f32 [K,N] -> f16 [N,K]) ----
    k_wconv<<<dim3(Dm / 32, Dm / 32, 6), 256, 0, stream>>>(Wk, wkh, Dm, Dm, 0);
    k_wconv<<<dim3(Dm / 32, Dm / 32, 6), 256, 0, stream>>>(Wv, wvh, Dm, Dm, 0);
    k_wconv<<<dim3(Dm / 32, Dm / 32, 6), 256, 0, stream>>>(Wo, woh, Dm, Dm, 0);
    k_wconv<<<dim3(DFFn / 32, Dm / 32, 4), 256, 0, stream>>>(W1, w1h, Dm, DFFn, 1);
    k_wconv<<<dim3(Dm / 32, DFFn / 32, 4), 256, 0, stream>>>(W2, w2h, DFFn, Dm, 1);

    const int n = (int)NE;
    k_copy2<<<n / 256, 256, 0, stream>>>(q_emb,  xbuf, xh, n);
    k_copy2<<<n / 256, 256, 0, stream>>>(qa_emb, ybuf, yh, n);

    auto gemm16 = [&](const f16* A, const f16* Bt, const float* bias, f16* C,
                      int M, int N, int K) {
        k_gemm<0, 1><<<dim3(N / 128, M / 128), 256, 0, stream>>>(A, Bt, bias, nullptr, C, M, N, K);
    };
    auto gemm32 = [&](const f16* A, const f16* Bt, const float* bias, float* C,
                      int M, int N, int K) {
        k_gemm<0, 0><<<dim3(N / 128, M / 128), 256, 0, stream>>>(A, Bt, bias, C, nullptr, M, N, K);
    };

    auto layer = [&](int l, int maskflag, float* Xq, f16* Xqh, f16* Xvh, bool apply_pos) {
        gemm16(Xqh, wkh + (size_t)l * WDD, bk + l * Dm, qh, MROWS, Dm, Dm);
        gemm16(Xvh, wvh + (size_t)l * WDD, bv + l * Dm, vh, MROWS, Dm, Dm);
        k_vt<<<Bsz * Hn * 8, 256, 0, stream>>>(vh, vt);
        k_attn<<<Bsz * Hn * 32, 256, 0, stream>>>(qh, vt, t1h, gam + l * Hn, maskflag);
        gemm32(t1h, woh + (size_t)l * WDD, bo + l * Dm, t2, MROWS, Dm, Dm);
        k_ln<<<MROWS / 4, 256, 0, stream>>>(t2, Xq, l1g + l * Dm, l1b + l * Dm, Xq, Xqh);
        if (apply_pos) {
            int sl = (l < 2) ? l : ((l + 1) >> 1);
            k_gemm<1, 1><<<dim3(DFFn / 128, MROWS / 128), 256, 0, stream>>>(
                Xqh, w1h + (size_t)sl * WDF, b1 + l * DFFn, nullptr, fbh, MROWS, DFFn, Dm);
            k_gemm<0, 0><<<dim3(Dm / 128, MROWS / 128), 256, 0, stream>>>(
                fbh, w2h + (size_t)sl * WDF, b2 + l * Dm, t2, nullptr, MROWS, Dm, DFFn);
            k_ln<<<MROWS / 4, 256, 0, stream>>>(t2, Xq, l2g + l * Dm, l2b + l * Dm, Xq, Xqh);
        }
    };

    // blocks_1: self-attn on y, mask=1, FFN
    layer(0, 1, ybuf, yh, yh, true);
    layer(1, 1, ybuf, yh, yh, true);
    // blocks_2: (mask=1, no FFN) then (mask=0, values=y, FFN), twice
    layer(2, 1, xbuf, xh, xh, false);
    layer(3, 0, xbuf, xh, yh, true);
    layer(4, 1, xbuf, xh, xh, false);
    layer(5, 0, xbuf, xh, yh, true);

    // outputs: (x, y) concatenated, f32
    k_copy<<<n / 256, 256, 0, stream>>>(xbuf, outp, n);
    k_copy<<<n / 256, 256, 0, stream>>>(ybuf, outp + NE, n);
}